// Round 4
// baseline (282.802 us; speedup 1.0000x reference)
//
#include <hip/hip_runtime.h>
#include <hip/hip_bf16.h>

#define N_TOKENS 16384
#define DIM      2048
#define NEXP     64
#define TOPK     8
#define BK       16
#define TM       256
#define NSLAB    16

// ---------------------------------------------------------------------------
// Kernel 1: router GEMM, fp32 (index stability requires fp32 logits; no
// fp32 MFMA on CDNA4 -> vector ALU, floor = 27.3 us chip-wide).
// R2's 8x8 micro-tile (VALU-issue is ~all FMA at this shape) + occupancy fix:
//   BK=16 -> LDS 21 KB; launch_bounds(256,4) -> VGPR<=128;
//   nslab=16 -> 1024 blocks = 4 blocks/CU = 16 waves/CU (2x R2).
// Register-level pipeline: next iter's global loads issued before compute,
// so HBM latency overlaps the 8x8 FMA block instead of serializing.
// LDS layouts give exactly 2-way bank aliasing everywhere (free per m136).
// ---------------------------------------------------------------------------
__global__ __launch_bounds__(256, 4) void gemm_kernel(const float* __restrict__ A,
                                                      const float* __restrict__ W,
                                                      float* __restrict__ out,
                                                      int k_len) {
    __shared__ float As[BK][260];   // [k][token], pad 260: staging writes 2-way
    __shared__ float Bs[BK][68];    // [k][expert]

    const int tid = threadIdx.x;
    const int r = tid >> 3;         // 0..31 token group (8 tokens)
    const int c = tid & 7;          // 0..7  expert group (8 experts)
    const int token_base = blockIdx.x * TM;
    const int k_start = blockIdx.y * k_len;
    out += (size_t)blockIdx.y * N_TOKENS * NEXP;

    const int arow = tid >> 2;            // 0..63 -> +64 per l
    const int akq  = (tid & 3) << 2;      // 0,4,8,12
    const float* aptr = A + (size_t)(token_base + arow) * DIM + akq;
    const float* wptr = W + (size_t)arow * DIM + akq;

    float acc[8][8] = {};
    float4 av[4], bv;

    // prologue: loads for iter 0
    #pragma unroll
    for (int l = 0; l < 4; ++l)
        av[l] = *(const float4*)(aptr + (size_t)l * 64 * DIM + k_start);
    bv = *(const float4*)(wptr + k_start);

    const int n_iters = k_len / BK;
    for (int it = 0; it < n_iters; ++it) {
        // write staged regs to LDS (transposed; 2-way banks = free)
        #pragma unroll
        for (int l = 0; l < 4; ++l) {
            float* dst = &As[0][0] + akq * 260 + (arow + l * 64);
            dst[0 * 260] = av[l].x; dst[1 * 260] = av[l].y;
            dst[2 * 260] = av[l].z; dst[3 * 260] = av[l].w;
        }
        {
            float* dst = &Bs[0][0] + akq * 68 + arow;
            dst[0 * 68] = bv.x; dst[1 * 68] = bv.y;
            dst[2 * 68] = bv.z; dst[3 * 68] = bv.w;
        }
        __syncthreads();

        // issue next iter's global loads now; they fly during compute
        if (it + 1 < n_iters) {
            int k0 = k_start + (it + 1) * BK;
            #pragma unroll
            for (int l = 0; l < 4; ++l)
                av[l] = *(const float4*)(aptr + (size_t)l * 64 * DIM + k0);
            bv = *(const float4*)(wptr + k0);
        }

        #pragma unroll 4
        for (int kk = 0; kk < BK; ++kk) {
            float4 a0 = *(const float4*)&As[kk][8 * r];
            float4 a1 = *(const float4*)&As[kk][8 * r + 4];
            float4 b0 = *(const float4*)&Bs[kk][8 * c];
            float4 b1 = *(const float4*)&Bs[kk][8 * c + 4];
            float a[8] = {a0.x, a0.y, a0.z, a0.w, a1.x, a1.y, a1.z, a1.w};
            float b[8] = {b0.x, b0.y, b0.z, b0.w, b1.x, b1.y, b1.z, b1.w};
            #pragma unroll
            for (int i = 0; i < 8; ++i)
                #pragma unroll
                for (int j = 0; j < 8; ++j)
                    acc[i][j] += a[i] * b[j];
        }
        __syncthreads();
    }

    #pragma unroll
    for (int i = 0; i < 8; ++i) {
        float* orow = out + (size_t)(token_base + 8 * r + i) * NEXP + 8 * c;
        *(float4*)(orow)     = make_float4(acc[i][0], acc[i][1], acc[i][2], acc[i][3]);
        *(float4*)(orow + 4) = make_float4(acc[i][4], acc[i][5], acc[i][6], acc[i][7]);
    }
}

// ---------------------------------------------------------------------------
// Kernel 2: slab-sum + softmax + top-8 via rank selection (lax.top_k
// semantics: sorted desc, ties -> lower index). 8192 waves, 2 tokens each.
// ---------------------------------------------------------------------------
__global__ __launch_bounds__(256) void topk_kernel(const float* __restrict__ logits,
                                                   int nslab,
                                                   float* __restrict__ out_w,
                                                   float* __restrict__ out_i,
                                                   float* __restrict__ cnt_ws,
                                                   float* __restrict__ sp_ws) {
    __shared__ float s_cnt[NEXP];
    __shared__ float s_sp[NEXP];
    if (threadIdx.x < NEXP) { s_cnt[threadIdx.x] = 0.f; s_sp[threadIdx.x] = 0.f; }
    __syncthreads();

    const int lane = threadIdx.x & 63;
    const int wave = blockIdx.x * 4 + (threadIdx.x >> 6);   // 0..8191
    const size_t slab_stride = (size_t)N_TOKENS * NEXP;

    float sp  = 0.f;
    float cnt = 0.f;

    for (int t = wave; t < N_TOKENS; t += 8192) {
        const float* p = logits + (size_t)t * NEXP + lane;
        float s0 = 0.f, s1 = 0.f, s2 = 0.f, s3 = 0.f;
        for (int s = 0; s < nslab; s += 4) {
            s0 += p[(size_t)(s + 0) * slab_stride];
            s1 += p[(size_t)(s + 1) * slab_stride];
            s2 += p[(size_t)(s + 2) * slab_stride];
            s3 += p[(size_t)(s + 3) * slab_stride];
        }
        float lg = (s0 + s1) + (s2 + s3);

        // softmax over 64 lanes
        float m = lg;
        #pragma unroll
        for (int off = 32; off; off >>= 1) m = fmaxf(m, __shfl_xor(m, off));
        float e = expf(lg - m);
        float ssum = e;
        #pragma unroll
        for (int off = 32; off; off >>= 1) ssum += __shfl_xor(ssum, off);
        float score = e / ssum;
        sp += score;

        // rank of this lane's score (64 independent, pipelined shuffles)
        int rank = 0;
        #pragma unroll
        for (int j = 0; j < 64; ++j) {
            float sj = __shfl(score, j);
            rank += (sj > score) || (sj == score && j < lane);
        }
        bool sel = rank < TOPK;

        float v = sel ? score : 0.f;
        #pragma unroll
        for (int off = 32; off; off >>= 1) v += __shfl_xor(v, off);

        if (sel) {
            out_w[(size_t)t * TOPK + rank] = score / v;
            out_i[(size_t)t * TOPK + rank] = (float)lane;
            cnt += 1.f;
        }
    }

    atomicAdd(&s_sp[lane], sp);
    atomicAdd(&s_cnt[lane], cnt);
    __syncthreads();
    if (threadIdx.x < 64)       atomicAdd(&cnt_ws[threadIdx.x], s_cnt[threadIdx.x]);
    else if (threadIdx.x < 128) atomicAdd(&sp_ws[threadIdx.x - 64], s_sp[threadIdx.x - 64]);
}

// ---------------------------------------------------------------------------
// Kernel 3: aux_loss = ALPHA * E * sum_e (cnt[e]/(N*K)) * (sum_prob[e]/N)
// ---------------------------------------------------------------------------
__global__ void finalize_kernel(const float* __restrict__ cnt_ws,
                                const float* __restrict__ sp_ws,
                                float* __restrict__ out_aux) {
    int lane = threadIdx.x;
    float v = (cnt_ws[lane] / (float)(N_TOKENS * TOPK)) *
              (sp_ws[lane] / (float)N_TOKENS);
    #pragma unroll
    for (int off = 32; off; off >>= 1) v += __shfl_xor(v, off);
    if (lane == 0) out_aux[0] = 0.001f * (float)NEXP * v;
}

extern "C" void kernel_launch(void* const* d_in, const int* in_sizes, int n_in,
                              void* d_out, int out_size, void* d_ws, size_t ws_size,
                              hipStream_t stream) {
    const float* A = (const float*)d_in[0];   // hidden_states (16384 x 2048)
    const float* W = (const float*)d_in[1];   // weight        (64 x 2048)
    float* out = (float*)d_out;

    const size_t logits_elems = (size_t)N_TOKENS * NEXP;
    const size_t logits_bytes = logits_elems * sizeof(float);

    int nslab = 4;
    if (ws_size >= 16 * logits_bytes + 1024)     nslab = 16;
    else if (ws_size >= 8 * logits_bytes + 1024) nslab = 8;

    float* l0     = (float*)d_ws;
    float* cnt_ws = (float*)((char*)d_ws + (size_t)nslab * logits_bytes);
    float* sp_ws  = cnt_ws + NEXP;

    hipMemsetAsync(cnt_ws, 0, 2 * NEXP * sizeof(float), stream);

    hipLaunchKernelGGL(gemm_kernel, dim3(N_TOKENS / TM, nslab), dim3(256), 0, stream,
                       A, W, l0, DIM / nslab);

    float* out_w = out;
    float* out_i = out + (size_t)N_TOKENS * TOPK;
    float* out_a = out + 2 * (size_t)N_TOKENS * TOPK;

    hipLaunchKernelGGL(topk_kernel, dim3(2048), dim3(256), 0, stream,
                       l0, nslab, out_w, out_i, cnt_ws, sp_ws);

    hipLaunchKernelGGL(finalize_kernel, dim3(1), dim3(64), 0, stream,
                       cnt_ws, sp_ws, out_a);
}